// Round 1
// baseline (3400.608 us; speedup 1.0000x reference)
//
#include <hip/hip_runtime.h>
#include <math.h>

// Problem constants (B=1)
#define T 2048
#define C 1024
#define H 16
#define HD 64
#define N3 (3*C)
#define NBLOCK 2048

// ---------------- histogram ----------------
__global__ void hist_kernel(const int* __restrict__ tok, float* __restrict__ cnt) {
    int i = blockIdx.x * blockDim.x + threadIdx.x;
    if (i < T) atomicAdd(&cnt[tok[i]], 1.0f);
}

// ---------------- scan: per_tok cumsum + pm gather ----------------
__global__ __launch_bounds__(256) void scan_kernel(const int* __restrict__ tok,
                                                   const float* __restrict__ cnt,
                                                   const float* __restrict__ padmask,
                                                   float* __restrict__ partial,
                                                   float* __restrict__ pm_tok) {
    __shared__ float sums[256];
    int tid = threadIdx.x;
    float vals[8];
    float s = 0.0f;
    #pragma unroll
    for (int j = 0; j < 8; ++j) {
        int t = tid * 8 + j;
        int tk = tok[t];
        float pt = 1.0f / (cnt[tk] + 1e-10f);
        s += pt;
        vals[j] = s;              // inclusive local prefix
        pm_tok[t] = padmask[tk];
    }
    sums[tid] = s;
    __syncthreads();
    // Hillis-Steele inclusive scan over 256 partials
    for (int off = 1; off < 256; off <<= 1) {
        float v = (tid >= off) ? sums[tid - off] : 0.0f;
        __syncthreads();
        sums[tid] += v;
        __syncthreads();
    }
    float offset = (tid > 0) ? sums[tid - 1] : 0.0f;
    #pragma unroll
    for (int j = 0; j < 8; ++j) partial[tid * 8 + j] = offset + vals[j];
}

// ---------------- fp32 tiled GEMM: C[M,N] = A[M,K] @ B[K,N] + bias[N] ----------------
__global__ __launch_bounds__(256) void gemm_f32(const float* __restrict__ A,
                                                const float* __restrict__ B,
                                                const float* __restrict__ bias,
                                                float* __restrict__ Cm,
                                                int M, int N, int K) {
    __shared__ float As[64][17];   // [row][k], +1 pad
    __shared__ float Bs[16][64];
    int tid = threadIdx.x;
    int n0 = blockIdx.x * 64, m0 = blockIdx.y * 64;
    int tx = tid & 15, ty = tid >> 4;
    float acc[4][4] = {};
    for (int k0 = 0; k0 < K; k0 += 16) {
        #pragma unroll
        for (int i = 0; i < 4; ++i) {
            int lin = tid + i * 256;
            int r = lin >> 4, c = lin & 15;
            As[r][c] = A[(m0 + r) * K + k0 + c];
        }
        #pragma unroll
        for (int i = 0; i < 4; ++i) {
            int lin = tid + i * 256;
            int r = lin >> 6, c = lin & 63;
            Bs[r][c] = B[(k0 + r) * N + n0 + c];
        }
        __syncthreads();
        #pragma unroll
        for (int kk = 0; kk < 16; ++kk) {
            float a[4], b[4];
            #pragma unroll
            for (int i = 0; i < 4; ++i) a[i] = As[ty * 4 + i][kk];
            #pragma unroll
            for (int j = 0; j < 4; ++j) b[j] = Bs[kk][tx * 4 + j];
            #pragma unroll
            for (int i = 0; i < 4; ++i)
                #pragma unroll
                for (int j = 0; j < 4; ++j) acc[i][j] += a[i] * b[j];
        }
        __syncthreads();
    }
    #pragma unroll
    for (int i = 0; i < 4; ++i) {
        int m = m0 + ty * 4 + i;
        #pragma unroll
        for (int j = 0; j < 4; ++j) {
            int n = n0 + tx * 4 + j;
            Cm[m * N + n] = acc[i][j] + bias[n];
        }
    }
}

// ---------------- RoPE + fixups, in place on qkv ----------------
// thread handles pair (d, d+32) of one (t, h) for q, k and v
__global__ __launch_bounds__(256) void rope_kernel(float* __restrict__ qkv,
                                                   const float* __restrict__ partial,
                                                   const float* __restrict__ cumsc) {
    int idx = blockIdx.x * blockDim.x + threadIdx.x;   // T * 512
    int t = idx >> 9;
    int r = idx & 511;       // h*32 + j
    int h = r >> 5, j = r & 31;
    int c1 = h * 64 + j, c2 = c1 + 32;
    float p = partial[t];
    // inv_freq = 10000^(-j/32)
    float inv = exp2f(-(float)j * (13.287712379549449f / 32.0f));
    float ang = p * inv;
    float cs = cosf(ang), sn = sinf(ang);
    float csc = cumsc[t];

    float* row = qkv + (size_t)t * N3;
    // q
    float q1 = row[c1], q2 = row[c2];
    float q1n = q1 * cs - q2 * sn;
    float q2n = q2 * cs + q1 * sn;
    if (j == 31) q2n = 1.0f;          // q[..., 63] = 1
    row[c1] = q1n; row[c2] = q2n;
    // k
    float k1 = row[C + c1], k2 = row[C + c2];
    float k1n = k1 * cs - k2 * sn;
    float k2n = k2 * cs + k1 * sn;
    if (j == 31) k2n = csc;           // k[..., 63] = cumulative_scores
    row[C + c1] = k1n; row[C + c2] = k2n;
    // v scaled by exp(cum)
    float ef = expf(csc);
    row[2 * C + c1] *= ef;
    row[2 * C + c2] *= ef;
}

// ---------------- flash attention, fp32 ----------------
// block: (h, q-tile of 64). 256 threads = 4 waves, wave handles 16 q rows.
__global__ __launch_bounds__(256) void attn_kernel(const float* __restrict__ qkv,
                                                   const float* __restrict__ pm_tok,
                                                   float* __restrict__ y) {
    __shared__ float Qs[64][65];
    __shared__ float Ks[64][65];
    __shared__ float Vs[64][64];
    __shared__ float Ps[4][16][64];
    int h = blockIdx.x;
    int q0 = blockIdx.y * 64;
    int tid = threadIdx.x;
    int wave = tid >> 6, lane = tid & 63;

    #pragma unroll
    for (int i = 0; i < 16; ++i) {
        int lin = tid + i * 256;
        int r = lin >> 6, c = lin & 63;
        Qs[r][c] = qkv[(size_t)(q0 + r) * N3 + h * 64 + c];
    }
    float m_run[16], l_run[16], acc[16], pmq[16];
    #pragma unroll
    for (int r = 0; r < 16; ++r) {
        m_run[r] = -INFINITY; l_run[r] = 0.0f; acc[r] = 0.0f;
        pmq[r] = pm_tok[q0 + wave * 16 + r];
    }
    __syncthreads();

    int kmax = q0 + 64;
    for (int k0 = 0; k0 < kmax; k0 += 64) {
        #pragma unroll
        for (int i = 0; i < 16; ++i) {
            int lin = tid + i * 256;
            int r = lin >> 6, c = lin & 63;
            Ks[r][c] = qkv[(size_t)(k0 + r) * N3 + C + h * 64 + c];
            Vs[r][c] = qkv[(size_t)(k0 + r) * N3 + 2 * C + h * 64 + c];
        }
        __syncthreads();
        int kg = k0 + lane;
        float pmk = pm_tok[kg];

        #pragma unroll
        for (int r = 0; r < 16; ++r) {
            int qg = q0 + wave * 16 + r;
            float s = 0.0f;
            #pragma unroll
            for (int d = 0; d < 64; ++d) s += Qs[wave * 16 + r][d] * Ks[lane][d];
            s *= 0.125f;
            bool masked = (kg > qg) || (pmq[r] * pmk == 0.0f);
            // wave max of (masked ? -inf : s)
            float sv = masked ? -INFINITY : s;
            float mt = sv;
            #pragma unroll
            for (int off = 32; off; off >>= 1) mt = fmaxf(mt, __shfl_xor(mt, off));
            float m_new = fmaxf(m_run[r], mt);
            float p = masked ? 0.0f : expf(s - m_new);
            float ps = p;
            #pragma unroll
            for (int off = 32; off; off >>= 1) ps += __shfl_xor(ps, off);
            float scale = (m_run[r] == -INFINITY) ? 0.0f : expf(m_run[r] - m_new);
            l_run[r] = l_run[r] * scale + ps;
            m_run[r] = m_new;
            Ps[wave][r][lane] = p;   // wave-local LDS, lockstep-safe
            float o = 0.0f;
            #pragma unroll
            for (int k = 0; k < 64; ++k) o += Ps[wave][r][k] * Vs[k][lane];
            acc[r] = acc[r] * scale + o;
        }
        __syncthreads();
    }
    #pragma unroll
    for (int r = 0; r < 16; ++r) {
        int qg = q0 + wave * 16 + r;
        y[(size_t)qg * C + h * 64 + lane] = acc[r] / l_run[r];
    }
}

extern "C" void kernel_launch(void* const* d_in, const int* in_sizes, int n_in,
                              void* d_out, int out_size, void* d_ws, size_t ws_size,
                              hipStream_t stream) {
    const float* x       = (const float*)d_in[0];
    const float* cumsc   = (const float*)d_in[1];
    const float* padmask = (const float*)d_in[2];
    const int*   tok     = (const int*)d_in[3];
    const float* w_attn  = (const float*)d_in[4];
    const float* b_attn  = (const float*)d_in[5];
    const float* w_proj  = (const float*)d_in[6];
    const float* b_proj  = (const float*)d_in[7];
    float* out = (float*)d_out;

    float* ws     = (float*)d_ws;
    float* cnt    = ws;                    // 2048
    float* part   = ws + 2048;             // 2048
    float* pm_tok = ws + 4096;             // 2048
    float* qkv    = ws + 6144;             // T*3C = 6,291,456
    float* y      = qkv + (size_t)T * N3;  // T*C  = 2,097,152

    hipMemsetAsync(cnt, 0, NBLOCK * sizeof(float), stream);
    hist_kernel<<<(T + 255) / 256, 256, 0, stream>>>(tok, cnt);
    scan_kernel<<<1, 256, 0, stream>>>(tok, cnt, padmask, part, pm_tok);

    gemm_f32<<<dim3(N3 / 64, T / 64), 256, 0, stream>>>(x, w_attn, b_attn, qkv, T, N3, C);
    rope_kernel<<<(T * 512) / 256, 256, 0, stream>>>(qkv, part, cumsc);
    attn_kernel<<<dim3(H, T / 64), 256, 0, stream>>>(qkv, pm_tok, y);
    gemm_f32<<<dim3(C / 64, T / 64), 256, 0, stream>>>(y, w_proj, b_proj, out, T, C, C);
}

// Round 2
// 261.189 us; speedup vs baseline: 13.0197x; 13.0197x over previous
//
#include <hip/hip_runtime.h>
#include <math.h>

// Problem constants (B=1)
#define T 2048
#define C 1024
#define H 16
#define HD 64
#define N3 (3*C)
#define NBLOCK 2048

typedef __attribute__((ext_vector_type(8))) short bf16x8;
typedef __attribute__((ext_vector_type(4))) short bf16x4;
typedef __attribute__((ext_vector_type(4))) float f32x4;

#define MFMA16(a, b, c) __builtin_amdgcn_mfma_f32_16x16x32_bf16((a), (b), (c), 0, 0, 0)

__device__ inline short f2bf(float f) {
    unsigned u; __builtin_memcpy(&u, &f, 4);
    unsigned r = (u + 0x7fffu + ((u >> 16) & 1u)) >> 16;
    return (short)r;
}
__device__ inline float bf2f(short s) {
    unsigned u = ((unsigned)(unsigned short)s) << 16;
    float f; __builtin_memcpy(&f, &u, 4);
    return f;
}

// ---------------- histogram ----------------
__global__ void hist_kernel(const int* __restrict__ tok, float* __restrict__ cnt) {
    int i = blockIdx.x * blockDim.x + threadIdx.x;
    if (i < T) atomicAdd(&cnt[tok[i]], 1.0f);
}

// ---------------- scan: per_tok cumsum + pm gather ----------------
__global__ __launch_bounds__(256) void scan_kernel(const int* __restrict__ tok,
                                                   const float* __restrict__ cnt,
                                                   const float* __restrict__ padmask,
                                                   float* __restrict__ partial,
                                                   float* __restrict__ pm_tok) {
    __shared__ float sums[256];
    int tid = threadIdx.x;
    float vals[8];
    float s = 0.0f;
    #pragma unroll
    for (int j = 0; j < 8; ++j) {
        int t = tid * 8 + j;
        int tk = tok[t];
        float pt = 1.0f / (cnt[tk] + 1e-10f);
        s += pt;
        vals[j] = s;
        pm_tok[t] = padmask[tk];
    }
    sums[tid] = s;
    __syncthreads();
    for (int off = 1; off < 256; off <<= 1) {
        float v = (tid >= off) ? sums[tid - off] : 0.0f;
        __syncthreads();
        sums[tid] += v;
        __syncthreads();
    }
    float offset = (tid > 0) ? sums[tid - 1] : 0.0f;
    #pragma unroll
    for (int j = 0; j < 8; ++j) partial[tid * 8 + j] = offset + vals[j];
}

// ---------------- fp32 -> bf16 convert ----------------
__global__ __launch_bounds__(256) void conv_bf16(const float* __restrict__ in,
                                                 short* __restrict__ out, int n) {
    int i = (blockIdx.x * blockDim.x + threadIdx.x) * 4;
    if (i < n) {
        float4 v = *(const float4*)(in + i);
        short4 o;
        o.x = f2bf(v.x); o.y = f2bf(v.y); o.z = f2bf(v.z); o.w = f2bf(v.w);
        *(short4*)(out + i) = o;
    }
}

// ---------------- transpose + convert: in [Kd][Nd] f32 -> out [Nd][Kd] bf16 ----------------
__global__ __launch_bounds__(256) void transp_bf16(const float* __restrict__ in,
                                                   short* __restrict__ out, int Kd, int Nd) {
    __shared__ float S[64][65];
    int n0 = blockIdx.x * 64, k0 = blockIdx.y * 64;
    int tid = threadIdx.x;
    #pragma unroll
    for (int i = 0; i < 16; ++i) {
        int lin = tid + i * 256;
        int r = lin >> 6, c = lin & 63;
        S[r][c] = in[(size_t)(k0 + r) * Nd + n0 + c];
    }
    __syncthreads();
    #pragma unroll
    for (int i = 0; i < 16; ++i) {
        int lin = tid + i * 256;
        int rn = lin >> 6, ck = lin & 63;
        out[(size_t)(n0 + rn) * Kd + k0 + ck] = f2bf(S[ck][rn]);
    }
}

// ---------------- bf16 GEMM (B^T): C[M,N] = A[M,K] @ Bt[N,K]^T + bias ----------------
// 128x128 tile, BK=32, 4 waves, 4x4 16x16x32 frags per wave
template <int OUT_BF16>
__global__ __launch_bounds__(256) void gemm_bt_bf16(const short* __restrict__ A,
                                                    const short* __restrict__ Bt,
                                                    const float* __restrict__ bias,
                                                    void* __restrict__ Cout,
                                                    int M, int N, int K) {
    __shared__ alignas(16) short As[128 * 32];
    __shared__ alignas(16) short Bs[128 * 32];
    int tid = threadIdx.x;
    int m0 = blockIdx.y * 128, n0 = blockIdx.x * 128;
    int w = tid >> 6, l = tid & 63;
    int wm = (w >> 1) * 64, wn = (w & 1) * 64;
    int lq = l & 15, g = l >> 4;
    f32x4 acc[4][4] = {};
    for (int k0 = 0; k0 < K; k0 += 32) {
        uint4 av[2], bv[2];
        #pragma unroll
        for (int i = 0; i < 2; ++i) {
            int off = (tid + i * 256) * 8;   // element offset in [128][32] tile
            int row = off >> 5, col = off & 31;
            av[i] = *(const uint4*)(A + (size_t)(m0 + row) * K + k0 + col);
            bv[i] = *(const uint4*)(Bt + (size_t)(n0 + row) * K + k0 + col);
        }
        __syncthreads();
        #pragma unroll
        for (int i = 0; i < 2; ++i) {
            int off = (tid + i * 256) * 8;
            *(uint4*)(As + off) = av[i];
            *(uint4*)(Bs + off) = bv[i];
        }
        __syncthreads();
        bf16x8 af[4], bfr[4];
        #pragma unroll
        for (int f = 0; f < 4; ++f) {
            af[f]  = *(const bf16x8*)(As + (wm + f * 16 + lq) * 32 + g * 8);
            bfr[f] = *(const bf16x8*)(Bs + (wn + f * 16 + lq) * 32 + g * 8);
        }
        #pragma unroll
        for (int fi = 0; fi < 4; ++fi)
            #pragma unroll
            for (int fj = 0; fj < 4; ++fj)
                acc[fi][fj] = MFMA16(af[fi], bfr[fj], acc[fi][fj]);
    }
    #pragma unroll
    for (int fi = 0; fi < 4; ++fi)
        #pragma unroll
        for (int fj = 0; fj < 4; ++fj)
            #pragma unroll
            for (int r = 0; r < 4; ++r) {
                int m = m0 + wm + fi * 16 + g * 4 + r;
                int n = n0 + wn + fj * 16 + lq;
                float v = acc[fi][fj][r] + bias[n];
                if (OUT_BF16) ((short*)Cout)[(size_t)m * N + n] = f2bf(v);
                else          ((float*)Cout)[(size_t)m * N + n] = v;
            }
}

// ---------------- RoPE + fixups, in place on bf16 qkv ----------------
__global__ __launch_bounds__(256) void rope_bf16(short* __restrict__ qkvb,
                                                 const float* __restrict__ partial,
                                                 const float* __restrict__ cumsc) {
    int idx = blockIdx.x * blockDim.x + threadIdx.x;   // T * 512
    int t = idx >> 9;
    int r = idx & 511;
    int hh = r >> 5, j = r & 31;
    int c1 = hh * 64 + j, c2 = c1 + 32;
    float p = partial[t];
    float inv = exp2f(-(float)j * (13.287712379549449f / 32.0f));  // 10000^(-j/32)
    float ang = p * inv;
    float cs = cosf(ang), sn = sinf(ang);
    float csc = cumsc[t];

    short* row = qkvb + (size_t)t * N3;
    // q
    float q1 = bf2f(row[c1]), q2 = bf2f(row[c2]);
    float q1n = q1 * cs - q2 * sn;
    float q2n = q2 * cs + q1 * sn;
    if (j == 31) q2n = 1.0f;
    row[c1] = f2bf(q1n); row[c2] = f2bf(q2n);
    // k
    float k1 = bf2f(row[C + c1]), k2 = bf2f(row[C + c2]);
    float k1n = k1 * cs - k2 * sn;
    float k2n = k2 * cs + k1 * sn;
    if (j == 31) k2n = csc;
    row[C + c1] = f2bf(k1n); row[C + c2] = f2bf(k2n);
    // v scaled by exp(cum)
    float ef = expf(csc);
    row[2 * C + c1] = f2bf(bf2f(row[2 * C + c1]) * ef);
    row[2 * C + c2] = f2bf(bf2f(row[2 * C + c2]) * ef);
}

// ---------------- per-head V transpose: qkvb v-section [T][64] -> vbT [h*64+d][T] ----------------
__global__ __launch_bounds__(256) void vtransp(const short* __restrict__ qkvb,
                                               short* __restrict__ vbT) {
    __shared__ short S[64][72];
    int h = blockIdx.x;
    int t0 = blockIdx.y * 64;
    int tid = threadIdx.x;
    #pragma unroll
    for (int i = 0; i < 16; ++i) {
        int lin = tid + i * 256;
        int r = lin >> 6, c = lin & 63;       // r: t-local, c: d
        S[r][c] = qkvb[(size_t)(t0 + r) * N3 + 2 * C + h * 64 + c];
    }
    __syncthreads();
    #pragma unroll
    for (int i = 0; i < 16; ++i) {
        int lin = tid + i * 256;
        int rd = lin >> 6, ct = lin & 63;     // rd: d, ct: t-local
        vbT[(size_t)(h * 64 + rd) * T + t0 + ct] = S[ct][rd];
    }
}

// ---------------- MFMA flash attention ----------------
// block = (head h, 64 q rows). 4 waves, wave w owns q rows [q0+16w, q0+16w+16).
// S^T = K·Q^T so each lane's 16 scores belong to ONE q row (softmax = 2 shfl).
__global__ __launch_bounds__(256) void attn_mfma(const short* __restrict__ qkvb,
                                                 const short* __restrict__ vbT,
                                                 const float* __restrict__ pm_tok,
                                                 short* __restrict__ yb) {
    __shared__ alignas(16) short Kt[64 * 64];         // [k][d], rows XOR-swizzled
    __shared__ alignas(16) short Vt[64 * 64];         // [d][k], rows XOR-swizzled
    __shared__ alignas(16) short Ps[4][16][72];       // per-wave P[q][k]
    __shared__ float pmS[64];

    int h = blockIdx.x;
    int q0 = ((int)gridDim.y - 1 - (int)blockIdx.y) * 64;   // long blocks first
    int tid = threadIdx.x;
    int w = tid >> 6, l = tid & 63;
    int lq = l & 15, g = l >> 4;

    // Q fragments live in registers the whole kernel (B operand of S^T mfma):
    // lane holds Q[q=lq][d = g*8 + j (+32)]
    int qrow = q0 + w * 16 + lq;
    const short* qbase = qkvb + (size_t)qrow * N3 + h * 64;
    bf16x8 qf0 = *(const bf16x8*)(qbase + g * 8);
    bf16x8 qf1 = *(const bf16x8*)(qbase + 32 + g * 8);
    float pmq = pm_tok[qrow];

    float m_run = -INFINITY, l_run = 0.0f;
    f32x4 accO[4] = {};   // [f]: d = 16f + lq ; rows q = 4g + r

    int ktiles = q0 / 64 + 1;
    for (int kt = 0; kt < ktiles; ++kt) {
        int k0 = kt * 64;
        __syncthreads();   // previous tile's LDS reads done
        {
            const short* kg = qkvb + (size_t)k0 * N3 + C + h * 64;
            #pragma unroll
            for (int i = 0; i < 2; ++i) {
                int off = (tid + i * 256) * 8;     // elems; 64 elems/row
                int row = off >> 6, col = off & 63;
                uint4 d = *(const uint4*)(kg + (size_t)row * N3 + col);
                int bo = (col * 2) ^ ((row & 7) << 4);
                *(uint4*)((char*)Kt + row * 128 + bo) = d;
            }
            const short* vg = vbT + (size_t)(h * 64) * T + k0;
            #pragma unroll
            for (int i = 0; i < 2; ++i) {
                int off = (tid + i * 256) * 8;
                int row = off >> 6, col = off & 63;  // row: d, col: k-local
                uint4 d = *(const uint4*)(vg + (size_t)row * T + col);
                int bo = (col * 2) ^ ((row & 7) << 4);
                *(uint4*)((char*)Vt + row * 128 + bo) = d;
            }
            if (tid < 64) pmS[tid] = pm_tok[k0 + tid];
        }
        __syncthreads();

        // ---- S^T = K · Q^T : 4 m-frags (k), 2 d-halves ----
        f32x4 s[4] = {};
        #pragma unroll
        for (int f = 0; f < 4; ++f) {
            int row = f * 16 + lq;                 // k-local
            const char* kr = (const char*)Kt + row * 128;
            int sw = (row & 7) << 4;
            bf16x8 a0 = *(const bf16x8*)(kr + ((g * 16) ^ sw));
            bf16x8 a1 = *(const bf16x8*)(kr + ((64 + g * 16) ^ sw));
            s[f] = MFMA16(a0, qf0, s[f]);
            s[f] = MFMA16(a1, qf1, s[f]);
        }

        // ---- mask + online softmax (lane holds 16 scores of q row lq) ----
        float smax = -INFINITY;
        #pragma unroll
        for (int f = 0; f < 4; ++f)
            #pragma unroll
            for (int r = 0; r < 4; ++r) {
                int kl = f * 16 + g * 4 + r;
                float sv = s[f][r] * 0.125f;
                bool msk = (k0 + kl > qrow) || (pmq * pmS[kl] == 0.0f);
                sv = msk ? -INFINITY : sv;
                s[f][r] = sv;
                smax = fmaxf(smax, sv);
            }
        smax = fmaxf(smax, __shfl_xor(smax, 16));
        smax = fmaxf(smax, __shfl_xor(smax, 32));
        float m_new = fmaxf(m_run, smax);
        float scale = (m_new == -INFINITY) ? 0.0f : __expf(m_run - m_new);
        float psum = 0.0f;
        float p[16];
        #pragma unroll
        for (int f = 0; f < 4; ++f)
            #pragma unroll
            for (int r = 0; r < 4; ++r) {
                float sv = s[f][r];
                float pv = (sv == -INFINITY) ? 0.0f : __expf(sv - m_new);
                p[f * 4 + r] = pv;
                psum += pv;
            }
        psum += __shfl_xor(psum, 16);
        psum += __shfl_xor(psum, 32);
        l_run = l_run * scale + psum;
        m_run = m_new;

        // rescale accO (rows q = 4g + r)
        float sc[4];
        #pragma unroll
        for (int r = 0; r < 4; ++r) sc[r] = __shfl(scale, g * 4 + r);
        #pragma unroll
        for (int f = 0; f < 4; ++f)
            #pragma unroll
            for (int r = 0; r < 4; ++r) accO[f][r] *= sc[r];

        // ---- P -> LDS (transpose to A-frag layout), wave-private ----
        #pragma unroll
        for (int f = 0; f < 4; ++f) {
            bf16x4 pk;
            #pragma unroll
            for (int r = 0; r < 4; ++r) pk[r] = f2bf(p[f * 4 + r]);
            *(bf16x4*)(&Ps[w][lq][f * 16 + g * 4]) = pk;
        }

        // ---- O += P · V : A = P[q][k] from Ps, B = V[k][d] from Vt[d][k] ----
        #pragma unroll
        for (int kh = 0; kh < 2; ++kh) {
            bf16x8 pa = *(const bf16x8*)(&Ps[w][lq][kh * 32 + g * 8]);
            #pragma unroll
            for (int f = 0; f < 4; ++f) {
                int vrow = f * 16 + lq;            // d
                const char* vr = (const char*)Vt + vrow * 128;
                bf16x8 vb = *(const bf16x8*)(vr + (((kh * 32 + g * 8) * 2) ^ ((vrow & 7) << 4)));
                accO[f] = MFMA16(pa, vb, accO[f]);
            }
        }
    }

    float linv[4];
    #pragma unroll
    for (int r = 0; r < 4; ++r) {
        float lr = __shfl(l_run, g * 4 + r);
        linv[r] = 1.0f / lr;
    }
    #pragma unroll
    for (int f = 0; f < 4; ++f)
        #pragma unroll
        for (int r = 0; r < 4; ++r) {
            int t = q0 + w * 16 + g * 4 + r;
            int col = h * 64 + f * 16 + lq;
            yb[(size_t)t * C + col] = f2bf(accO[f][r] * linv[r]);
        }
}

extern "C" void kernel_launch(void* const* d_in, const int* in_sizes, int n_in,
                              void* d_out, int out_size, void* d_ws, size_t ws_size,
                              hipStream_t stream) {
    const float* x       = (const float*)d_in[0];
    const float* cumsc   = (const float*)d_in[1];
    const float* padmask = (const float*)d_in[2];
    const int*   tok     = (const int*)d_in[3];
    const float* w_attn  = (const float*)d_in[4];
    const float* b_attn  = (const float*)d_in[5];
    const float* w_proj  = (const float*)d_in[6];
    const float* b_proj  = (const float*)d_in[7];
    float* out = (float*)d_out;

    float* cnt    = (float*)d_ws;                 // 2048
    float* part   = cnt + 2048;                   // 2048
    float* pm_tok = part + 2048;                  // 2048
    short* xb     = (short*)(pm_tok + 2048);      // T*C
    short* wabT   = xb + (size_t)T * C;           // 3C*C
    short* wpbT   = wabT + (size_t)N3 * C;        // C*C
    short* qkvb   = wpbT + (size_t)C * C;         // T*3C
    short* vbT    = qkvb + (size_t)T * N3;        // C*T
    short* yb     = vbT + (size_t)C * T;          // T*C

    hipMemsetAsync(cnt, 0, NBLOCK * sizeof(float), stream);
    hist_kernel<<<(T + 255) / 256, 256, 0, stream>>>(tok, cnt);
    scan_kernel<<<1, 256, 0, stream>>>(tok, cnt, padmask, part, pm_tok);

    conv_bf16<<<(T * C / 4 + 255) / 256, 256, 0, stream>>>(x, xb, T * C);
    transp_bf16<<<dim3(N3 / 64, C / 64), 256, 0, stream>>>(w_attn, wabT, C, N3);
    transp_bf16<<<dim3(C / 64, C / 64), 256, 0, stream>>>(w_proj, wpbT, C, C);

    gemm_bt_bf16<1><<<dim3(N3 / 128, T / 128), 256, 0, stream>>>(xb, wabT, b_attn, qkvb, T, N3, C);
    rope_bf16<<<(T * 512) / 256, 256, 0, stream>>>(qkvb, part, cumsc);
    vtransp<<<dim3(H, T / 64), 256, 0, stream>>>(qkvb, vbT);
    attn_mfma<<<dim3(H, T / 64), 256, 0, stream>>>(qkvb, vbT, pm_tok, yb);
    gemm_bt_bf16<0><<<dim3(C / 128, T / 128), 256, 0, stream>>>(yb, wpbT, b_proj, out, T, C, C);
}

// Round 3
// 139.019 us; speedup vs baseline: 24.4615x; 1.8788x over previous
//
#include <hip/hip_runtime.h>
#include <math.h>

// Problem constants (B=1)
#define T 2048
#define C 1024
#define H 16
#define HD 64
#define N3 (3*C)
#define NBLOCK 2048

typedef __attribute__((ext_vector_type(8))) short bf16x8;
typedef __attribute__((ext_vector_type(4))) short bf16x4;
typedef __attribute__((ext_vector_type(4))) float f32x4;

#define MFMA16(a, b, c) __builtin_amdgcn_mfma_f32_16x16x32_bf16((a), (b), (c), 0, 0, 0)

__device__ inline short f2bf(float f) {
    unsigned u; __builtin_memcpy(&u, &f, 4);
    unsigned r = (u + 0x7fffu + ((u >> 16) & 1u)) >> 16;
    return (short)r;
}
__device__ inline float bf2f(short s) {
    unsigned u = ((unsigned)(unsigned short)s) << 16;
    float f; __builtin_memcpy(&f, &u, 4);
    return f;
}

// async global->LDS, 16B per lane. lds base must be wave-uniform; HW adds lane*16.
__device__ inline void gload_lds16(const void* g, void* l) {
    __builtin_amdgcn_global_load_lds((const __attribute__((address_space(1))) unsigned int*)g,
                                     (__attribute__((address_space(3))) unsigned int*)l,
                                     16, 0, 0);
}

// ---------------- fused histogram + scan + pm gather (1 block) ----------------
__global__ __launch_bounds__(256) void prep_kernel(const int* __restrict__ tok,
                                                   const float* __restrict__ padmask,
                                                   float* __restrict__ partial,
                                                   float* __restrict__ pm_tok) {
    __shared__ float cntS[NBLOCK];
    __shared__ float sums[256];
    int tid = threadIdx.x;
    #pragma unroll
    for (int j = 0; j < 8; ++j) cntS[tid * 8 + j] = 0.0f;
    __syncthreads();
    int tk[8];
    #pragma unroll
    for (int j = 0; j < 8; ++j) {
        tk[j] = tok[tid * 8 + j];
        atomicAdd(&cntS[tk[j]], 1.0f);
    }
    __syncthreads();
    float vals[8];
    float s = 0.0f;
    #pragma unroll
    for (int j = 0; j < 8; ++j) {
        s += 1.0f / (cntS[tk[j]] + 1e-10f);
        vals[j] = s;
        pm_tok[tid * 8 + j] = padmask[tk[j]];
    }
    sums[tid] = s;
    __syncthreads();
    for (int off = 1; off < 256; off <<= 1) {
        float v = (tid >= off) ? sums[tid - off] : 0.0f;
        __syncthreads();
        sums[tid] += v;
        __syncthreads();
    }
    float offset = (tid > 0) ? sums[tid - 1] : 0.0f;
    #pragma unroll
    for (int j = 0; j < 8; ++j) partial[tid * 8 + j] = offset + vals[j];
}

// ---------------- fp32 -> bf16 convert ----------------
__global__ __launch_bounds__(256) void conv_bf16(const float* __restrict__ in,
                                                 short* __restrict__ out, int n) {
    int i = (blockIdx.x * blockDim.x + threadIdx.x) * 4;
    if (i < n) {
        float4 v = *(const float4*)(in + i);
        short4 o;
        o.x = f2bf(v.x); o.y = f2bf(v.y); o.z = f2bf(v.z); o.w = f2bf(v.w);
        *(short4*)(out + i) = o;
    }
}

// ---------------- transpose + convert: in [Kd][Nd] f32 -> out [Nd][Kd] bf16 ----------------
__global__ __launch_bounds__(256) void transp_bf16(const float* __restrict__ in,
                                                   short* __restrict__ out, int Kd, int Nd) {
    __shared__ float S[64][65];
    int n0 = blockIdx.x * 64, k0 = blockIdx.y * 64;
    int tid = threadIdx.x;
    #pragma unroll
    for (int i = 0; i < 16; ++i) {
        int lin = tid + i * 256;
        int r = lin >> 6, c = lin & 63;
        S[r][c] = in[(size_t)(k0 + r) * Nd + n0 + c];
    }
    __syncthreads();
    #pragma unroll
    for (int i = 0; i < 16; ++i) {
        int lin = tid + i * 256;
        int rn = lin >> 6, ck = lin & 63;
        out[(size_t)(n0 + rn) * Kd + k0 + ck] = f2bf(S[ck][rn]);
    }
}

// ---------------- bf16 GEMM (B^T, global_load_lds staging, m97 structure) ----------------
// 128 x (BNF*32) tile, BK=32, 4 waves (2x2), 4 x BNF 16x16x32 frags per wave
template <int OUT_BF16, int BNF>
__global__ __launch_bounds__(256) void gemm_bt(const short* __restrict__ A,
                                               const short* __restrict__ Bt,
                                               const float* __restrict__ bias,
                                               void* __restrict__ Cout,
                                               int M, int N, int K) {
    constexpr int BN = BNF * 32;
    __shared__ alignas(16) short As[128 * 32];
    __shared__ alignas(16) short Bs[BN * 32];
    int tid = threadIdx.x;
    int m0 = blockIdx.y * 128, n0 = blockIdx.x * BN;
    int w = tid >> 6, l = tid & 63;
    int wm = (w >> 1) * 64, wn = (w & 1) * (BNF * 16);
    int lq = l & 15, g = l >> 4;
    int prow = l >> 2, pcol = (l & 3) * 8;    // lane's slot within a 1KB chunk (16 rows x 32 cols)
    f32x4 acc[4][BNF] = {};
    for (int k0 = 0; k0 < K; k0 += 32) {
        #pragma unroll
        for (int i = 0; i < 2; ++i) {
            int c = w * 2 + i;
            int row = c * 16 + prow;
            gload_lds16(A + (size_t)(m0 + row) * K + k0 + pcol, As + c * 512);
        }
        #pragma unroll
        for (int i = 0; i < BNF / 2; ++i) {
            int c = w * (BNF / 2) + i;
            int row = c * 16 + prow;
            gload_lds16(Bt + (size_t)(n0 + row) * K + k0 + pcol, Bs + c * 512);
        }
        __syncthreads();
        bf16x8 af[4], bfr[BNF];
        #pragma unroll
        for (int f = 0; f < 4; ++f)
            af[f] = *(const bf16x8*)(As + (wm + f * 16 + lq) * 32 + g * 8);
        #pragma unroll
        for (int j = 0; j < BNF; ++j)
            bfr[j] = *(const bf16x8*)(Bs + (wn + j * 16 + lq) * 32 + g * 8);
        #pragma unroll
        for (int fi = 0; fi < 4; ++fi)
            #pragma unroll
            for (int fj = 0; fj < BNF; ++fj)
                acc[fi][fj] = MFMA16(af[fi], bfr[fj], acc[fi][fj]);
        __syncthreads();
    }
    #pragma unroll
    for (int fi = 0; fi < 4; ++fi)
        #pragma unroll
        for (int fj = 0; fj < BNF; ++fj)
            #pragma unroll
            for (int r = 0; r < 4; ++r) {
                int m = m0 + wm + fi * 16 + g * 4 + r;
                int n = n0 + wn + fj * 16 + lq;
                float v = acc[fi][fj][r] + bias[n];
                if (OUT_BF16) ((short*)Cout)[(size_t)m * N + n] = f2bf(v);
                else          ((float*)Cout)[(size_t)m * N + n] = v;
            }
}

// ---------------- RoPE on q,k only (v handled in vtransp_scale) ----------------
__global__ __launch_bounds__(256) void rope_qk(short* __restrict__ qkvb,
                                               const float* __restrict__ partial,
                                               const float* __restrict__ cumsc) {
    int idx = blockIdx.x * blockDim.x + threadIdx.x;   // T * 512
    int t = idx >> 9;
    int r = idx & 511;
    int hh = r >> 5, j = r & 31;
    int c1 = hh * 64 + j, c2 = c1 + 32;
    float p = partial[t];
    float inv = exp2f(-(float)j * (13.287712379549449f / 32.0f));  // 10000^(-j/32)
    float ang = p * inv;
    float cs = cosf(ang), sn = sinf(ang);
    float csc = cumsc[t];

    short* row = qkvb + (size_t)t * N3;
    float q1 = bf2f(row[c1]), q2 = bf2f(row[c2]);
    float q1n = q1 * cs - q2 * sn;
    float q2n = q2 * cs + q1 * sn;
    if (j == 31) q2n = 1.0f;
    row[c1] = f2bf(q1n); row[c2] = f2bf(q2n);

    float k1 = bf2f(row[C + c1]), k2 = bf2f(row[C + c2]);
    float k1n = k1 * cs - k2 * sn;
    float k2n = k2 * cs + k1 * sn;
    if (j == 31) k2n = csc;
    row[C + c1] = f2bf(k1n); row[C + c2] = f2bf(k2n);
}

// ---------------- per-head V transpose + exp(cum) scale ----------------
__global__ __launch_bounds__(256) void vtransp_scale(const short* __restrict__ qkvb,
                                                     const float* __restrict__ cumsc,
                                                     short* __restrict__ vbT) {
    __shared__ short S[64][72];
    __shared__ float efs[64];
    int h = blockIdx.x;
    int t0 = blockIdx.y * 64;
    int tid = threadIdx.x;
    if (tid < 64) efs[tid] = __expf(cumsc[t0 + tid]);
    __syncthreads();
    #pragma unroll
    for (int i = 0; i < 16; ++i) {
        int lin = tid + i * 256;
        int r = lin >> 6, c = lin & 63;       // r: t-local, c: d
        S[r][c] = f2bf(bf2f(qkvb[(size_t)(t0 + r) * N3 + 2 * C + h * 64 + c]) * efs[r]);
    }
    __syncthreads();
    #pragma unroll
    for (int i = 0; i < 16; ++i) {
        int lin = tid + i * 256;
        int rd = lin >> 6, ct = lin & 63;     // rd: d, ct: t-local
        vbT[(size_t)(h * 64 + rd) * T + t0 + ct] = S[ct][rd];
    }
}

// ---------------- MFMA flash attention, double-buffered + reg prefetch ----------------
// 512 blocks (snake-ordered work units), 4 waves, wave w owns 16 q rows.
__global__ __launch_bounds__(256) void attn_mfma(const short* __restrict__ qkvb,
                                                 const short* __restrict__ vbT,
                                                 const float* __restrict__ pm_tok,
                                                 short* __restrict__ yb) {
    __shared__ alignas(16) short Kt[2][64 * 64];      // [k][d], XOR-swizzled rows
    __shared__ alignas(16) short Vt[2][64 * 64];      // [d][k], XOR-swizzled rows
    __shared__ alignas(16) short Ps[4][16][72];       // per-wave P[q][k]
    __shared__ float pmS[2][64];

    int bid = blockIdx.x;
    int u = (bid < 256) ? bid : 767 - bid;            // snake: pair long+short units
    int h = u & 15;
    int q0 = (31 - (u >> 4)) * 64;                    // u=0 -> longest (q0=1984)
    int tid = threadIdx.x;
    int w = tid >> 6, l = tid & 63;
    int lq = l & 15, g = l >> 4;

    int qrow = q0 + w * 16 + lq;
    const short* qbase = qkvb + (size_t)qrow * N3 + h * 64;
    bf16x8 qf0 = *(const bf16x8*)(qbase + g * 8);
    bf16x8 qf1 = *(const bf16x8*)(qbase + 32 + g * 8);
    float pmq = pm_tok[qrow];

    float m_run = -INFINITY, l_run = 0.0f;
    f32x4 accO[4] = {};   // [f]: d = 16f + lq ; rows q = 4g + r

    int nt = q0 / 64 + 1;

    // staging geometry: thread covers rows srow, srow+32; 8 cols at scol
    int srow = tid >> 3, scol = (tid & 7) * 8;
    const short* kgb = qkvb + C + h * 64 + scol;
    const short* vgb = vbT + (size_t)(h * 64) * T + scol;
    int wb0 = srow * 128 + ((scol * 2) ^ ((srow & 7) << 4));
    int wb1 = (srow + 32) * 128 + ((scol * 2) ^ ((srow & 7) << 4));

    uint4 kr0, kr1, vr0, vr1;
    float pmr = 1.0f;

    // prologue: tile 0
    kr0 = *(const uint4*)(kgb + (size_t)srow * N3);
    kr1 = *(const uint4*)(kgb + (size_t)(srow + 32) * N3);
    vr0 = *(const uint4*)(vgb + (size_t)srow * T);
    vr1 = *(const uint4*)(vgb + (size_t)(srow + 32) * T);
    if (tid < 64) pmr = pm_tok[tid];
    *(uint4*)((char*)Kt[0] + wb0) = kr0;
    *(uint4*)((char*)Kt[0] + wb1) = kr1;
    *(uint4*)((char*)Vt[0] + wb0) = vr0;
    *(uint4*)((char*)Vt[0] + wb1) = vr1;
    if (tid < 64) pmS[0][tid] = pmr;
    __syncthreads();

    for (int t = 0; t < nt; ++t) {
        int cur = t & 1;
        int k0 = t * 64;
        bool pf = (t + 1 < nt);
        if (pf) {   // issue prefetch loads for tile t+1 (latency hides under compute)
            int kn = k0 + 64;
            kr0 = *(const uint4*)(kgb + (size_t)(kn + srow) * N3);
            kr1 = *(const uint4*)(kgb + (size_t)(kn + srow + 32) * N3);
            vr0 = *(const uint4*)(vgb + (size_t)srow * T + kn);
            vr1 = *(const uint4*)(vgb + (size_t)(srow + 32) * T + kn);
            if (tid < 64) pmr = pm_tok[kn + tid];
        }
        const char* Kc = (const char*)Kt[cur];
        const char* Vc = (const char*)Vt[cur];

        // ---- S^T = K · Q^T ----
        f32x4 s[4] = {};
        #pragma unroll
        for (int f = 0; f < 4; ++f) {
            int row = f * 16 + lq;
            const char* kr_ = Kc + row * 128;
            int sw = (row & 7) << 4;
            bf16x8 a0 = *(const bf16x8*)(kr_ + ((g * 16) ^ sw));
            bf16x8 a1 = *(const bf16x8*)(kr_ + ((64 + g * 16) ^ sw));
            s[f] = MFMA16(a0, qf0, s[f]);
            s[f] = MFMA16(a1, qf1, s[f]);
        }

        // ---- mask + online softmax (lane holds 16 scores of q row lq) ----
        float smax = -INFINITY;
        #pragma unroll
        for (int f = 0; f < 4; ++f)
            #pragma unroll
            for (int r = 0; r < 4; ++r) {
                int kl = f * 16 + g * 4 + r;
                float sv = s[f][r] * 0.125f;
                bool msk = (k0 + kl > qrow) || (pmq * pmS[cur][kl] == 0.0f);
                sv = msk ? -INFINITY : sv;
                s[f][r] = sv;
                smax = fmaxf(smax, sv);
            }
        smax = fmaxf(smax, __shfl_xor(smax, 16));
        smax = fmaxf(smax, __shfl_xor(smax, 32));
        float m_new = fmaxf(m_run, smax);
        float scale = (m_new == -INFINITY) ? 0.0f : __expf(m_run - m_new);
        float psum = 0.0f;
        float p[16];
        #pragma unroll
        for (int f = 0; f < 4; ++f)
            #pragma unroll
            for (int r = 0; r < 4; ++r) {
                float sv = s[f][r];
                float pv = (sv == -INFINITY) ? 0.0f : __expf(sv - m_new);
                p[f * 4 + r] = pv;
                psum += pv;
            }
        psum += __shfl_xor(psum, 16);
        psum += __shfl_xor(psum, 32);
        l_run = l_run * scale + psum;
        m_run = m_new;

        float sc[4];
        #pragma unroll
        for (int r = 0; r < 4; ++r) sc[r] = __shfl(scale, g * 4 + r);
        #pragma unroll
        for (int f = 0; f < 4; ++f)
            #pragma unroll
            for (int r = 0; r < 4; ++r) accO[f][r] *= sc[r];

        // ---- P -> LDS (wave-private transpose to A-frag layout) ----
        #pragma unroll
        for (int f = 0; f < 4; ++f) {
            bf16x4 pk;
            #pragma unroll
            for (int r = 0; r < 4; ++r) pk[r] = f2bf(p[f * 4 + r]);
            *(bf16x4*)(&Ps[w][lq][f * 16 + g * 4]) = pk;
        }

        // ---- O += P · V ----
        #pragma unroll
        for (int kh = 0; kh < 2; ++kh) {
            bf16x8 pa = *(const bf16x8*)(&Ps[w][lq][kh * 32 + g * 8]);
            #pragma unroll
            for (int f = 0; f < 4; ++f) {
                int vrow = f * 16 + lq;
                const char* vr_ = Vc + vrow * 128;
                bf16x8 vb = *(const bf16x8*)(vr_ + (((kh * 32 + g * 8) * 2) ^ ((vrow & 7) << 4)));
                accO[f] = MFMA16(pa, vb, accO[f]);
            }
        }

        // ---- write prefetched tile into the other buffer ----
        if (pf) {
            int nxt = 1 - cur;
            *(uint4*)((char*)Kt[nxt] + wb0) = kr0;
            *(uint4*)((char*)Kt[nxt] + wb1) = kr1;
            *(uint4*)((char*)Vt[nxt] + wb0) = vr0;
            *(uint4*)((char*)Vt[nxt] + wb1) = vr1;
            if (tid < 64) pmS[nxt][tid] = pmr;
        }
        __syncthreads();
    }

    float linv[4];
    #pragma unroll
    for (int r = 0; r < 4; ++r) linv[r] = 1.0f / __shfl(l_run, g * 4 + r);
    #pragma unroll
    for (int f = 0; f < 4; ++f)
        #pragma unroll
        for (int r = 0; r < 4; ++r) {
            int t = q0 + w * 16 + g * 4 + r;
            int col = h * 64 + f * 16 + lq;
            yb[(size_t)t * C + col] = f2bf(accO[f][r] * linv[r]);
        }
}

extern "C" void kernel_launch(void* const* d_in, const int* in_sizes, int n_in,
                              void* d_out, int out_size, void* d_ws, size_t ws_size,
                              hipStream_t stream) {
    const float* x       = (const float*)d_in[0];
    const float* cumsc   = (const float*)d_in[1];
    const float* padmask = (const float*)d_in[2];
    const int*   tok     = (const int*)d_in[3];
    const float* w_attn  = (const float*)d_in[4];
    const float* b_attn  = (const float*)d_in[5];
    const float* w_proj  = (const float*)d_in[6];
    const float* b_proj  = (const float*)d_in[7];
    float* out = (float*)d_out;

    float* part   = (float*)d_ws;                 // 2048
    float* pm_tok = part + 2048;                  // 2048
    short* xb     = (short*)(pm_tok + 2048);      // T*C
    short* wabT   = xb + (size_t)T * C;           // 3C*C
    short* wpbT   = wabT + (size_t)N3 * C;        // C*C
    short* qkvb   = wpbT + (size_t)C * C;         // T*3C
    short* vbT    = qkvb + (size_t)T * N3;        // C*T
    short* yb     = vbT + (size_t)C * T;          // T*C

    prep_kernel<<<1, 256, 0, stream>>>(tok, padmask, part, pm_tok);
    conv_bf16<<<(T * C / 4 + 255) / 256, 256, 0, stream>>>(x, xb, T * C);
    transp_bf16<<<dim3(N3 / 64, C / 64), 256, 0, stream>>>(w_attn, wabT, C, N3);
    transp_bf16<<<dim3(C / 64, C / 64), 256, 0, stream>>>(w_proj, wpbT, C, C);

    gemm_bt<1, 4><<<dim3(N3 / 128, T / 128), 256, 0, stream>>>(xb, wabT, b_attn, qkvb, T, N3, C);
    rope_qk<<<(T * 512) / 256, 256, 0, stream>>>(qkvb, part, cumsc);
    vtransp_scale<<<dim3(H, T / 64), 256, 0, stream>>>(qkvb, cumsc, vbT);
    attn_mfma<<<512, 256, 0, stream>>>(qkvb, vbT, pm_tok, yb);
    gemm_bt<0, 2><<<dim3(C / 64, T / 128), 256, 0, stream>>>(yb, wpbT, b_proj, out, T, C, C);
}